// Round 9
// baseline (755.515 us; speedup 1.0000x reference)
//
#include <hip/hip_runtime.h>
#include <hip/hip_bf16.h>
#include <math.h>

// Problem dims
#define S_LEN   4096
#define B_SZ    2
#define E_DIM   1024
#define H_HEADS 8
#define R_ROUNDS 2
#define C_CHUNK 64
#define D_HEAD  128
#define NC_CHUNKS 64
#define QV_STRIDE 2048              // q (1024) | v (1024) per row
#define SCALE_F 0.08838834764831845f
#define NEG_F (-1e9f)
#define NEG_SELF_F (-1e5f)

typedef __attribute__((ext_vector_type(8))) short short8;
typedef __attribute__((ext_vector_type(4))) float f32x4;

// fp32 -> bf16 (RNE) bit pattern
__device__ inline unsigned bfr(float x){
  unsigned u = __float_as_uint(x);
  return (u + 0x7fffu + ((u >> 16) & 1u)) >> 16;
}
__device__ inline unsigned bpack2(float a, float b){ return bfr(a) | (bfr(b) << 16); }
__device__ inline float bf2f(unsigned short v){ return __uint_as_float((unsigned)v << 16); }

// LDS column remap for 128-wide fp32 GEMM tiles
__device__ inline int sm_col(int c){ return ((c & 4) << 4) | ((c >> 3) << 2) | (c & 3); }

// ---------- fp32 q-projection body (R1-exact; 220us, conflicts 0) ----------
// Single fp32 FMA chain per output, k ascending — mirrors CPU sgemm so q
// feeding the discrete hash argmax matches reference rounding.
// CHAIN ORDER IS SACRED. History: R7 swizzle (12.6M conflicts -> 0);
// R8 dbuf neutral; R9-R12 (global-A, 16x8 tile) all regressed — the
// LDS-return-path wall (8 waves x 4 ds_read_b128 x 12cy = 384cy vs 256cy
// FMA per CU per kk = 66% VALUBusy) is the practical floor at this
// problem's grid geometry. R13: revert to R1-exact; fuse v-proj into the
// same dispatch (separate pipe — MFMA vs VALU, m114 co-schedule).
__device__ inline void pref4(float4 (&va)[4], float4 (&vw)[4],
                             const float* __restrict__ Ap, const float* __restrict__ Wp,
                             int kt, int K){
  #pragma unroll
  for (int ii=0; ii<4; ii++){
    va[ii] = *(const float4*)(Ap + kt + (size_t)ii*32*K);
    vw[ii] = *(const float4*)(Wp + kt + (size_t)ii*32*K);
  }
}

__device__ inline void stage4(float (*a_s)[132], float (*w_s)[132],
                              const float4 (&va)[4], const float4 (&vw)[4],
                              int srow, int scol, int swz){
  #pragma unroll
  for (int ii=0; ii<4; ii++){
    int cp = sm_col(srow + ii*32) ^ swz;   // swz = (t&7)<<2 == f(scol+j) for j=0..3
    a_s[scol+0][cp]=va[ii].x; a_s[scol+1][cp]=va[ii].y; a_s[scol+2][cp]=va[ii].z; a_s[scol+3][cp]=va[ii].w;
    w_s[scol+0][cp]=vw[ii].x; w_s[scol+1][cp]=vw[ii].y; w_s[scol+2][cp]=vw[ii].z; w_s[scol+3][cp]=vw[ii].w;
  }
}

__device__ inline void comp32(const float (*a_s)[132], const float (*w_s)[132],
                              float (&acc)[8][8], int tx, int ty){
  #pragma unroll 4
  for (int kk=0; kk<32; kk++){
    int fk = ((kk>>2)&7)<<2;               // must match store-side swizzle
    int ca = (ty*4) ^ fk;
    int cw = (tx*4) ^ fk;
    float4 a0  = *(const float4*)&a_s[kk][ca];
    float4 a1  = *(const float4*)&a_s[kk][64+ca];
    float4 w0v = *(const float4*)&w_s[kk][cw];
    float4 w1v = *(const float4*)&w_s[kk][64+cw];
    float am[8] = {a0.x,a0.y,a0.z,a0.w,a1.x,a1.y,a1.z,a1.w};
    float wm[8] = {w0v.x,w0v.y,w0v.z,w0v.w,w1v.x,w1v.y,w1v.z,w1v.w};
    #pragma unroll
    for (int i=0;i<8;i++)
      #pragma unroll
      for (int j=0;j<8;j++)
        acc[i][j] = fmaf(am[i], wm[j], acc[i][j]);
  }
}

__device__ void qproj_f32_body(const float* __restrict__ A, const float* __restrict__ W,
                               const float* __restrict__ bia, float* __restrict__ Cout,
                               int K, int ldc, int m0, int n0, unsigned char* smem)
{
  float (*a_s)[132] = (float(*)[132])smem;                 // 16896 B
  float (*w_s)[132] = (float(*)[132])(smem + 16896);       // 16896 B
  const int t  = threadIdx.x;
  const int tx = t & 15, ty = t >> 4;

  float acc[8][8];
  #pragma unroll
  for (int i=0;i<8;i++)
    #pragma unroll
    for (int j=0;j<8;j++) acc[i][j]=0.f;

  const int srow = t >> 3;
  const int scol = (t & 7) * 4;
  const int swz  = (t & 7) << 2;

  const float* Ap = A + (size_t)(m0 + srow)*K + scol;
  const float* Wp = W + (size_t)(n0 + srow)*K + scol;

  float4 va[4], vw[4], vb[4], wb[4];
  pref4(va, vw, Ap, Wp, 0, K);

  for (int kt = 0; kt < K; kt += 64){
    pref4(vb, wb, Ap, Wp, kt+32, K);       // kt+32 < K always (K multiple of 64)
    stage4(a_s, w_s, va, vw, srow, scol, swz);
    __syncthreads();
    comp32(a_s, w_s, acc, tx, ty);
    __syncthreads();
    if (kt + 64 < K) pref4(va, vw, Ap, Wp, kt+64, K);
    stage4(a_s, w_s, vb, wb, srow, scol, swz);
    __syncthreads();
    comp32(a_s, w_s, acc, tx, ty);
    __syncthreads();
  }

  float bias[8];
  #pragma unroll
  for (int j=0;j<8;j++) bias[j] = bia[n0 + tx*8 + j];
  #pragma unroll
  for (int i=0;i<8;i++){
    int row = m0 + ty*8 + i;
    float4 o0 = {acc[i][0]+bias[0], acc[i][1]+bias[1], acc[i][2]+bias[2], acc[i][3]+bias[3]};
    float4 o1 = {acc[i][4]+bias[4], acc[i][5]+bias[5], acc[i][6]+bias[6], acc[i][7]+bias[7]};
    *(float4*)(Cout + (size_t)row*ldc + n0 + tx*8)     = o0;
    *(float4*)(Cout + (size_t)row*ldc + n0 + tx*8 + 4) = o1;
  }
}

// ---------- bf16 MFMA GEMM body (R6-validated, unchanged) ----------
#define BST 72
__device__ void gemm_bf16_body(const float* __restrict__ A, const float* __restrict__ W,
                               const float* __restrict__ bias, float* __restrict__ C,
                               int K, int ldc, int m0, int n0,
                               unsigned short* a_sh, unsigned short* w_sh)
{
  const int t = threadIdx.x;
  const int lane = t & 63, wid = t >> 6;
  const int mw = (wid >> 1) * 64, nw = (wid & 1) * 64;
  const int lr = lane & 15, lg = lane >> 4;

  f32x4 acc[4][4];
  #pragma unroll
  for (int i=0;i<4;i++)
    #pragma unroll
    for (int j=0;j<4;j++) acc[i][j] = (f32x4){0.f,0.f,0.f,0.f};

  const int srow = t >> 3;
  const int scol = (t & 7) * 8;

  for (int kt = 0; kt < K; kt += 64){
    __syncthreads();
    #pragma unroll
    for (int ii = 0; ii < 4; ii++){
      int row = srow + ii*32;
      const float4 f0 = *(const float4*)(A + (size_t)(m0+row)*K + kt + scol);
      const float4 f1 = *(const float4*)(A + (size_t)(m0+row)*K + kt + scol + 4);
      uint4 ua = { bpack2(f0.x,f0.y), bpack2(f0.z,f0.w), bpack2(f1.x,f1.y), bpack2(f1.z,f1.w) };
      *(uint4*)&a_sh[row*BST + scol] = ua;
      const float4 g0 = *(const float4*)(W + (size_t)(n0+row)*K + kt + scol);
      const float4 g1 = *(const float4*)(W + (size_t)(n0+row)*K + kt + scol + 4);
      uint4 uw = { bpack2(g0.x,g0.y), bpack2(g0.z,g0.w), bpack2(g1.x,g1.y), bpack2(g1.z,g1.w) };
      *(uint4*)&w_sh[row*BST + scol] = uw;
    }
    __syncthreads();
    #pragma unroll
    for (int ks = 0; ks < 64; ks += 32){
      short8 af[4], bw[4];
      #pragma unroll
      for (int i=0;i<4;i++) af[i] = *(const short8*)&a_sh[(mw + i*16 + lr)*BST + ks + lg*8];
      #pragma unroll
      for (int j=0;j<4;j++) bw[j] = *(const short8*)&w_sh[(nw + j*16 + lr)*BST + ks + lg*8];
      #pragma unroll
      for (int i=0;i<4;i++)
        #pragma unroll
        for (int j=0;j<4;j++)
          acc[i][j] = __builtin_amdgcn_mfma_f32_16x16x32_bf16(af[i], bw[j], acc[i][j], 0, 0, 0);
    }
  }
  #pragma unroll
  for (int j=0;j<4;j++){
    int col = n0 + nw + j*16 + lr;
    float bs = bias[col];
    #pragma unroll
    for (int i=0;i<4;i++){
      int rbase = m0 + mw + i*16 + lg*4;
      #pragma unroll
      for (int r=0;r<4;r++)
        C[(size_t)(rbase+r)*ldc + col] = acc[i][j][r] + bs;
    }
  }
}

// ---------- fused q-proj (f32) + v-proj (bf16) — independent, different pipes ----------
// by < 64: f32 q-proj block; by >= 64: bf16 v-proj block. LDS is a union
// (36864 B = bf16 need; f32 uses 33792). f32 is VALU/LDS-bound (MfmaUtil 0),
// bf16 is MFMA-bound — co-resident blocks overlap per m114 (max, not sum).
__global__ __launch_bounds__(256) void proj_fused_kernel(
    const float* __restrict__ x,
    const float* __restrict__ wq, const float* __restrict__ bq,
    const float* __restrict__ wv, const float* __restrict__ bv,
    float* __restrict__ qv)
{
  __shared__ __align__(16) unsigned char smem[36864];
  const int by = blockIdx.y;
  if (by < 64){
    qproj_f32_body(x, wq, bq, qv, 1024, QV_STRIDE, by*128, blockIdx.x*128, smem);
  } else {
    unsigned short* a_sh = (unsigned short*)smem;            // 18432 B
    unsigned short* w_sh = (unsigned short*)(smem + 18432);  // 18432 B
    gemm_bf16_body(x, wv, bv, qv + 1024, 1024, QV_STRIDE, (by-64)*128, blockIdx.x*128, a_sh, w_sh);
  }
}

// ---------- standalone bf16 GEMM (out-proj) ----------
__global__ __launch_bounds__(256) void gemm_bf16_kernel(
    const float* __restrict__ A, const float* __restrict__ W,
    const float* __restrict__ bias, float* __restrict__ C,
    int K, int ldc)
{
  __shared__ unsigned short a_sh[128*BST];
  __shared__ unsigned short w_sh[128*BST];
  gemm_bf16_body(A, W, bias, C, K, ldc, blockIdx.y*128, blockIdx.x*128, a_sh, w_sh);
}

// ---------- per-row norm over E ----------
__global__ __launch_bounds__(256) void invnorm_kernel(const float* __restrict__ qv,
                                                      float* __restrict__ invn,
                                                      float* __restrict__ nrm)
{
  int row = blockIdx.x;
  int t = threadIdx.x;
  float4 v = *(const float4*)(qv + (size_t)row*QV_STRIDE + t*4);
  float ss = v.x*v.x + v.y*v.y + v.z*v.z + v.w*v.w;
  #pragma unroll
  for (int off=32; off; off>>=1) ss += __shfl_down(ss, off);
  __shared__ float part[4];
  if ((t & 63)==0) part[t>>6] = ss;
  __syncthreads();
  if (t==0){
    float n = sqrtf(part[0]+part[1]+part[2]+part[3]);
    nrm[row]  = n;
    invn[row] = 1.0f/n;
  }
}

// ---------- fp32 hash path, reference-order mimicry (R5 pass; DO NOT TOUCH) ----------
__global__ __launch_bounds__(256) void hash32_kernel(
    const float* __restrict__ qv, const float* __restrict__ nrm,
    const float* __restrict__ hw, int* __restrict__ hashes)
{
  int idx = blockIdx.x*256 + threadIdx.x;
  int s = idx & (S_LEN-1);
  int h = (idx >> 12) & 7;
  int r = (idx >> 15) & 1;
  int b = idx >> 16;
  const float* qr = qv + (size_t)(s*B_SZ + b)*QV_STRIDE + h*D_HEAD;
  const float  n  = nrm[s*B_SZ + b];
  const float* wp = hw + (size_t)(r*H_HEADS + h)*D_HEAD*8;
  float lin[8];
  #pragma unroll
  for (int m=0;m<8;m++) lin[m]=0.f;
  for (int d=0; d<D_HEAD; d++){
    float kd = qr[d] / n;
    #pragma unroll
    for (int m=0;m<8;m++) lin[m] = fmaf(kd, wp[d*8+m], lin[m]);
  }
  float best = lin[0]; int bi = 0;
  #pragma unroll
  for (int m=1;m<8;m++) if (lin[m] > best){ best=lin[m]; bi=m; }
  #pragma unroll
  for (int m=0;m<8;m++) if (-lin[m] > best){ best=-lin[m]; bi=8+m; }
  hashes[idx] = bi;
}

// ---------- stable counting sort by bucket, per (b,r,h) ----------
__global__ __launch_bounds__(256) void sort_kernel(const int* __restrict__ hashes,
                                                   int* __restrict__ sidx,
                                                   unsigned short* __restrict__ hs_pack)
{
  __shared__ unsigned char bucket_s[S_LEN];
  __shared__ int counts[16][257];
  __shared__ int bbase[16];
  int t = threadIdx.x;
  size_t base = (size_t)blockIdx.x * S_LEN;
  for (int e=0;e<16;e++) bucket_s[t + e*256] = (unsigned char)hashes[base + t + e*256];
  #pragma unroll
  for (int u=0;u<16;u++) counts[u][t]=0;
  if (t<16) counts[t][256]=0;
  __syncthreads();
  int s0 = t*16;
  for (int e=0;e<16;e++){ int u = bucket_s[s0+e]; counts[u][t]++; }
  __syncthreads();
  if (t < 16){
    int run=0;
    for (int tt=0; tt<256; tt++){ int c = counts[t][tt]; counts[t][tt]=run; run+=c; }
    counts[t][256]=run;
  }
  __syncthreads();
  if (t==0){
    int run=0;
    for (int u=0;u<16;u++){ bbase[u]=run; run += counts[u][256]; }
  }
  __syncthreads();
  for (int e=0;e<16;e++){
    int s = s0+e; int u = bucket_s[s];
    int pos = bbase[u] + counts[u][t]; counts[u][t]++;
    sidx[base+pos] = s;
    hs_pack[base+pos] = (unsigned short)(s | (u<<12));
  }
}

// ---------- gather: sorted bf16 K-hat rows + transposed V ----------
// ksort[brh][pos][d]  = q[token][h,d] * invn[token]   (bf16)
// vsortT[brh][d][pos] = v[token][h,d]                 (bf16, transposed in LDS)
#define GST 136
__global__ __launch_bounds__(256) void gather_kernel(
    const float* __restrict__ qv, const float* __restrict__ invn,
    const int* __restrict__ sidx,
    unsigned short* __restrict__ ksort, unsigned short* __restrict__ vsortT)
{
  __shared__ int tok_s[256];
  __shared__ float sc_s[256];
  __shared__ unsigned short v_sub[64*GST];
  const int t = threadIdx.x;
  const int brh = blockIdx.x >> 4, pc = blockIdx.x & 15;
  const int b = brh >> 4;
  const int h = brh & 7;
  const size_t base_s = (size_t)brh * S_LEN;
  const int pos0 = pc * 256;
  {
    int tok = sidx[base_s + pos0 + t];
    tok_s[t] = tok;
    sc_s[t] = invn[tok*B_SZ + b];
  }
  __syncthreads();
  // ksort: coalesced row-major bf16
  #pragma unroll 4
  for (int i=0;i<16;i++){
    int slot = i*256 + t;
    int pos = slot >> 4, g = slot & 15;
    int tok = tok_s[pos]; float sc = sc_s[pos];
    const float* src = qv + ((size_t)tok*B_SZ + b)*QV_STRIDE + h*D_HEAD + g*8;
    float4 f0 = *(const float4*)src, f1 = *(const float4*)(src+4);
    uint4 u = { bpack2(f0.x*sc, f0.y*sc), bpack2(f0.z*sc, f0.w*sc),
                bpack2(f1.x*sc, f1.y*sc), bpack2(f1.z*sc, f1.w*sc) };
    *(uint4*)&ksort[(base_s + pos0 + pos)*128 + g*8] = u;
  }
  // vsortT: 4 sub-tiles of 64 pos, LDS transpose
  for (int sub=0; sub<4; sub++){
    __syncthreads();
    #pragma unroll
    for (int i=0;i<4;i++){
      int slot = i*256 + t;
      int pr = slot >> 4, g = slot & 15;
      int tok = tok_s[sub*64 + pr];
      const float* src = qv + ((size_t)tok*B_SZ + b)*QV_STRIDE + 1024 + h*D_HEAD + g*8;
      float4 f0 = *(const float4*)src, f1 = *(const float4*)(src+4);
      uint4 u = { bpack2(f0.x,f0.y), bpack2(f0.z,f0.w), bpack2(f1.x,f1.y), bpack2(f1.z,f1.w) };
      *(uint4*)&v_sub[pr*GST + g*8] = u;
    }
    __syncthreads();
    #pragma unroll
    for (int i=0;i<8;i++){
      int oslot = i*256 + t;             // 2048 = 128 d x 16 pos-groups
      int d = oslot >> 4, p4 = (oslot & 15)*4;
      unsigned a0 = v_sub[(p4+0)*GST + d];
      unsigned a1 = v_sub[(p4+1)*GST + d];
      unsigned a2 = v_sub[(p4+2)*GST + d];
      unsigned a3 = v_sub[(p4+3)*GST + d];
      uint2 o = { a0 | (a1<<16), a2 | (a3<<16) };
      *(uint2*)&vsortT[(size_t)brh*524288 + (size_t)d*4096 + pos0 + sub*64 + p4] = o;
    }
  }
}

// ---------- MFMA chunked LSH attention ----------
// Reference quirk (silent broadcast): for query at sorted position p=n*64+c,
// scores/values use win(n), but BOTH masks compare vs win(c).
// S rows post-scaled by SCALE*nrm[token] (Q = k-hat * SCALE*nrm exactly up to
// smooth fp noise). Full 192-wide softmax in registers; P via LDS (bf16).
#define KST 136
#define VST 72
#define PST 200
__device__ inline int swzg(int row, int g){ return (g ^ (row & 7)) << 3; }

__global__ __launch_bounds__(256) void attn_mfma_kernel(
    const unsigned short* __restrict__ ksort, const unsigned short* __restrict__ vsortT,
    const float* __restrict__ nrm, const unsigned short* __restrict__ hs_pack,
    unsigned short* __restrict__ o_r16, float* __restrict__ lse_g)
{
  __shared__ unsigned short kv_un[128*VST];          // 9216 u16: K chunk (64x136) or V^T chunk (128x72)
  __shared__ unsigned short p_sh[64*PST];
  __shared__ __align__(16) unsigned short pack_s[S_LEN];
  __shared__ float srow_s[64];

  const int t = threadIdx.x;
  const int bid = blockIdx.x;
  const int nc = bid & 63;
  const int brh = bid >> 6;
  const int b = brh >> 4;
  const size_t base_s = (size_t)brh * S_LEN;

  {
    const uint4* src = (const uint4*)(hs_pack + base_s);
    uint4* dst = (uint4*)pack_s;
    dst[t]       = src[t];
    dst[256 + t] = src[256 + t];
  }
  __syncthreads();
  if (t < 64){
    int tok = pack_s[nc*64 + t] & 0xfff;
    srow_s[t] = SCALE_F * nrm[tok*B_SZ + b];
  }

  const int lane = t & 63, wid = t >> 6;
  const int mw = wid * 16;                 // wave's 16 query rows
  const int lr = lane & 15, lg = lane >> 4;

  f32x4 acc[12];
  #pragma unroll
  for (int i=0;i<12;i++) acc[i] = (f32x4){0.f,0.f,0.f,0.f};
  short8 aq[4];

  // ---- QK^T: window chunks, w=1 first (supplies Q fragments) ----
  const int worder[3] = {1, 0, 2};
  #pragma unroll
  for (int wi=0; wi<3; wi++){
    int w = worder[wi];
    int cwch = (nc + w + 63) & 63;
    __syncthreads();                       // also covers srow_s on first iter
    #pragma unroll
    for (int i=0;i<4;i++){
      int slot = i*256 + t;
      int row = slot >> 4, g = slot & 15;
      uint4 u = *(const uint4*)&ksort[(base_s + cwch*64 + row)*128 + g*8];
      *(uint4*)&kv_un[row*KST + swzg(row, g)] = u;
    }
    __syncthreads();
    if (wi==0){
      #pragma unroll
      for (int ks=0; ks<4; ks++)
        aq[ks] = *(const short8*)&kv_un[(mw+lr)*KST + swzg(mw+lr, ks*4+lg)];
    }
    #pragma unroll
    for (int ks=0; ks<4; ks++){
      #pragma unroll
      for (int k4=0; k4<4; k4++){
        short8 bk = *(const short8*)&kv_un[(k4*16+lr)*KST + swzg(k4*16+lr, ks*4+lg)];
        acc[w*4+k4] = __builtin_amdgcn_mfma_f32_16x16x32_bf16(aq[ks], bk, acc[w*4+k4], 0,0,0);
      }
    }
  }

  // ---- scale + masks + softmax (C-layout: col=lr, rows mw+lg*4+r) ----
  unsigned pq[4]; float sr[4]; int c_[4]; float linv[4];
  #pragma unroll
  for (int r=0;r<4;r++){
    c_[r] = mw + lg*4 + r;
    pq[r] = pack_s[nc*64 + c_[r]];
    sr[r] = srow_s[c_[r]];
  }
  #pragma unroll
  for (int ti=0; ti<12; ti++){
    int w = ti >> 2, k4 = ti & 3;
    #pragma unroll
    for (int r=0;r<4;r++){
      int mc = (c_[r] + w + 63) & 63;
      unsigned e = pack_s[mc*64 + k4*16 + lr];
      float s = acc[ti][r] * sr[r];
      s = ((e>>12) == (pq[r]>>12)) ? s : NEG_F;
      if ((e & 0xfffu) == (pq[r] & 0xfffu)) s = NEG_SELF_F;
      acc[ti][r] = s;
    }
  }
  #pragma unroll
  for (int r=0;r<4;r++){
    float m = acc[0][r];
    #pragma unroll
    for (int ti=1; ti<12; ti++) m = fmaxf(m, acc[ti][r]);
    #pragma unroll
    for (int off=1; off<16; off<<=1) m = fmaxf(m, __shfl_xor(m, off));
    float l = 0.f;
    #pragma unroll
    for (int ti=0; ti<12; ti++){
      float p = __expf(acc[ti][r] - m);
      l += p;
      int wpos = (ti>>2)*64 + (ti&3)*16 + lr;
      p_sh[c_[r]*PST + (((wpos>>3) ^ (c_[r]&7))<<3) + (wpos&7)] = (unsigned short)bfr(p);
    }
    #pragma unroll
    for (int off=1; off<16; off<<=1) l += __shfl_xor(l, off);
    linv[r] = 1.0f / l;
    if (lr == 0) lse_g[base_s + (pq[r] & 0xfffu)] = m + logf(l);
  }

  // ---- PV ----
  f32x4 oacc[8];
  #pragma unroll
  for (int i=0;i<8;i++) oacc[i] = (f32x4){0.f,0.f,0.f,0.f};
  for (int w=0; w<3; w++){
    int cwch = (nc + w + 63) & 63;
    __syncthreads();                       // p_sh written; kv_un free
    #pragma unroll
    for (int i=0;i<4;i++){
      int slot = i*256 + t;                // 1024 = 128 d x 8 key-groups
      int d = slot >> 3, kg = slot & 7;
      uint4 u = *(const uint4*)&vsortT[(size_t)brh*524288 + (size_t)d*4096 + cwch*64 + kg*8];
      *(uint4*)&kv_un[d*VST + swzg(d, kg)] = u;
    }
    __syncthreads();
    short8 ap[2];
    #pragma unroll
    for (int ks=0; ks<2; ks++){
      int g = w*8 + ks*4 + lg;
      ap[ks] = *(const short8*)&p_sh[(mw+lr)*PST + ((g ^ ((mw+lr)&7))<<3)];
    }
    #pragma unroll
    for (int ks=0; ks<2; ks++)
      #pragma unroll
      for (int dt=0; dt<8; dt++){
        short8 bv = *(const short8*)&kv_un[(dt*16+lr)*VST + swzg(dt*16+lr, ks*4+lg)];
        oacc[dt] = __builtin_amdgcn_mfma_f32_16x16x32_bf16(ap[ks], bv, oacc[dt], 0,0,0);
      }
  }

  // ---- epilogue: bf16 scatter by token ----
  #pragma unroll
  for (int r=0;r<4;r++){
    int tok = pq[r] & 0xfff;
    size_t ob = (base_s + tok) * 128;
    #pragma unroll
    for (int dt=0; dt<8; dt++)
      o_r16[ob + dt*16 + lr] = (unsigned short)bfr(oacc[dt][r] * linv[r]);
  }
}

// ---------- combine rounds: softmax over per-round LSE (o_r now bf16) ----------
__global__ __launch_bounds__(256) void combine_kernel(const unsigned short* __restrict__ o_r16,
                                                      const float* __restrict__ lse,
                                                      float* __restrict__ ocomb)
{
  int gid = blockIdx.x*256 + threadIdx.x;
  int q4 = gid & 31;
  int tokenid = gid >> 5;
  int s = tokenid & (S_LEN-1);
  int h = (tokenid >> 12) & 7;
  int b = tokenid >> 15;
  size_t i0 = (size_t)((b*2 + 0)*8 + h)*S_LEN + s;
  size_t i1 = (size_t)((b*2 + 1)*8 + h)*S_LEN + s;
  float l0 = lse[i0], l1 = lse[i1];
  float m = fmaxf(l0,l1);
  float w0 = expf(l0-m), w1 = expf(l1-m);
  float inv = 1.0f/(w0+w1);
  w0*=inv; w1*=inv;
  const unsigned short* p0 = o_r16 + i0*128 + q4*4;
  const unsigned short* p1 = o_r16 + i1*128 + q4*4;
  float4 o = { w0*bf2f(p0[0]) + w1*bf2f(p1[0]),
               w0*bf2f(p0[1]) + w1*bf2f(p1[1]),
               w0*bf2f(p0[2]) + w1*bf2f(p1[2]),
               w0*bf2f(p0[3]) + w1*bf2f(p1[3]) };
  *(float4*)(ocomb + (size_t)(s*B_SZ + b)*E_DIM + h*D_HEAD + q4*4) = o;
}

// ---------- launch ----------
extern "C" void kernel_launch(void* const* d_in, const int* in_sizes, int n_in,
                              void* d_out, int out_size, void* d_ws, size_t ws_size,
                              hipStream_t stream)
{
  (void)in_sizes; (void)n_in; (void)out_size; (void)ws_size;
  const float* x  = (const float*)d_in[0];
  const float* wq = (const float*)d_in[1];
  const float* bq = (const float*)d_in[2];
  const float* wv = (const float*)d_in[3];
  const float* bv = (const float*)d_in[4];
  const float* wo = (const float*)d_in[5];
  const float* bo = (const float*)d_in[6];
  const float* hw = (const float*)d_in[7];
  float* out = (float*)d_out;

  float* ws    = (float*)d_ws;
  float* qv    = ws;                          // [8192][2048] q|v fp32
  float* invn  = ws + 16777216;               // [8192]
  float* nrm   = ws + 16785408;               // [8192]
  int*   hashes= (int*)(ws + 16793600);       // [B,R,H,S]
  int*   sidx  = (int*)(ws + 16924672);       // [B,R,H,S]
  float* lse   = ws + 17055744;               // [B,R,H,S]
  unsigned short* o_r16   = (unsigned short*)(ws + 17186816);  // [32][4096][128] bf16
  unsigned short* ksort   = (unsigned short*)(ws + 25575424);  // [32][4096][128] bf16
  float* ocomb = ws + 33964032;               // [8192][1024] fp32
  unsigned short* vsortT  = (unsigned short*)(ws + 33964032);  // [32][128][4096] bf16 (overlays ocomb; dead before combine writes)
  unsigned short* hs_pack = (unsigned short*)(ws + 42352640);  // [B,R,H,S] packed

  proj_fused_kernel<<<dim3(8,128), 256, 0, stream>>>(x, wq, bq, wv, bv, qv);
  invnorm_kernel<<<dim3(8192), 256, 0, stream>>>(qv, invn, nrm);
  hash32_kernel<<<dim3(512), 256, 0, stream>>>(qv, nrm, hw, hashes);
  sort_kernel<<<dim3(32), 256, 0, stream>>>(hashes, sidx, hs_pack);
  gather_kernel<<<dim3(512), 256, 0, stream>>>(qv, invn, sidx, ksort, vsortT);
  attn_mfma_kernel<<<dim3(2048), 256, 0, stream>>>(ksort, vsortT, nrm, hs_pack, o_r16, lse);
  combine_kernel<<<dim3(8192), 256, 0, stream>>>(o_r16, lse, ocomb);
  gemm_bf16_kernel<<<dim3(8,64), 256, 0, stream>>>(ocomb, wo, bo, out, 1024, 1024);
}

// Round 10
// 599.210 us; speedup vs baseline: 1.2609x; 1.2609x over previous
//
#include <hip/hip_runtime.h>
#include <hip/hip_bf16.h>
#include <math.h>

// Problem dims
#define S_LEN   4096
#define B_SZ    2
#define E_DIM   1024
#define H_HEADS 8
#define R_ROUNDS 2
#define C_CHUNK 64
#define D_HEAD  128
#define NC_CHUNKS 64
#define QV_STRIDE 2048              // q (1024) | v (1024) per row
#define SCALE_F 0.08838834764831845f
#define NEG_F (-1e9f)
#define NEG_SELF_F (-1e5f)

typedef __attribute__((ext_vector_type(8))) short short8;
typedef __attribute__((ext_vector_type(4))) float f32x4;

// fp32 -> bf16 (RNE) bit pattern
__device__ inline unsigned bfr(float x){
  unsigned u = __float_as_uint(x);
  return (u + 0x7fffu + ((u >> 16) & 1u)) >> 16;
}
__device__ inline unsigned bpack2(float a, float b){ return bfr(a) | (bfr(b) << 16); }
__device__ inline float bf2f(unsigned short v){ return __uint_as_float((unsigned)v << 16); }

// LDS column remap for 128-wide fp32 GEMM tiles
__device__ inline int sm_col(int c){ return ((c & 4) << 4) | ((c >> 3) << 2) | (c & 3); }

// ---------- fp32 tiled GEMM (q projection ONLY) — R2-best, 219.5us ----------
// Single fp32 FMA chain per output, k ascending — mirrors CPU sgemm so q
// feeding the discrete hash argmax matches reference rounding.
// CHAIN ORDER IS SACRED. History: R7 swizzle (12.6M conflicts -> 0, 220us);
// R8 dbuf (neutral, kept); R9-R12 global-A / 16x8-tile / R13 fusion ALL
// regressed. The LDS-return-path wall (8 waves x 4 ds_read_b128 x 12cy =
// 384cy vs 256cy FMA per CU per kk = 66% VALUBusy) is this kernel's
// practical floor at this grid geometry. PARKED — do not re-attempt
// without a fundamentally new mechanism.
__device__ inline void pref4(float4 (&va)[4], float4 (&vw)[4],
                             const float* __restrict__ Ap, const float* __restrict__ Wp,
                             int kt, int K){
  #pragma unroll
  for (int ii=0; ii<4; ii++){
    va[ii] = *(const float4*)(Ap + kt + (size_t)ii*32*K);
    vw[ii] = *(const float4*)(Wp + kt + (size_t)ii*32*K);
  }
}

__device__ inline void stage4(float (*a_s)[128], float (*w_s)[128],
                              const float4 (&va)[4], const float4 (&vw)[4],
                              int srow, int scol, int swz){
  #pragma unroll
  for (int ii=0; ii<4; ii++){
    int cp = sm_col(srow + ii*32) ^ swz;   // swz = (t&7)<<2 == f(scol+j) for j=0..3
    a_s[scol+0][cp]=va[ii].x; a_s[scol+1][cp]=va[ii].y; a_s[scol+2][cp]=va[ii].z; a_s[scol+3][cp]=va[ii].w;
    w_s[scol+0][cp]=vw[ii].x; w_s[scol+1][cp]=vw[ii].y; w_s[scol+2][cp]=vw[ii].z; w_s[scol+3][cp]=vw[ii].w;
  }
}

__device__ inline void comp32(const float (*a_s)[128], const float (*w_s)[128],
                              float (&acc)[8][8], int tx, int ty){
  #pragma unroll 4
  for (int kk=0; kk<32; kk++){
    int fk = ((kk>>2)&7)<<2;               // must match store-side swizzle
    int ca = (ty*4) ^ fk;
    int cw = (tx*4) ^ fk;
    float4 a0  = *(const float4*)&a_s[kk][ca];
    float4 a1  = *(const float4*)&a_s[kk][64+ca];
    float4 w0v = *(const float4*)&w_s[kk][cw];
    float4 w1v = *(const float4*)&w_s[kk][64+cw];
    float am[8] = {a0.x,a0.y,a0.z,a0.w,a1.x,a1.y,a1.z,a1.w};
    float wm[8] = {w0v.x,w0v.y,w0v.z,w0v.w,w1v.x,w1v.y,w1v.z,w1v.w};
    #pragma unroll
    for (int i=0;i<8;i++)
      #pragma unroll
      for (int j=0;j<8;j++)
        acc[i][j] = fmaf(am[i], wm[j], acc[i][j]);
  }
}

__global__ __launch_bounds__(256) void gemm_f32_kernel(
    const float* __restrict__ A, const float* __restrict__ W, const float* __restrict__ bia,
    float* __restrict__ Cout, int N, int K, int ldc)
{
  __shared__ __align__(16) float a_s[2][32][128];
  __shared__ __align__(16) float w_s[2][32][128];
  const int t  = threadIdx.x;
  const int n0 = blockIdx.x * 128;
  const int m0 = blockIdx.y * 128;
  const int tx = t & 15, ty = t >> 4;

  float acc[8][8];
  #pragma unroll
  for (int i=0;i<8;i++)
    #pragma unroll
    for (int j=0;j<8;j++) acc[i][j]=0.f;

  const int srow = t >> 3;
  const int scol = (t & 7) * 4;
  const int swz  = (t & 7) << 2;

  const float* Ap = A + (size_t)(m0 + srow)*K + scol;
  const float* Wp = W + (size_t)(n0 + srow)*K + scol;

  float4 va[4], vw[4];
  pref4(va, vw, Ap, Wp, 0, K);
  stage4(a_s[0], w_s[0], va, vw, srow, scol, swz);
  pref4(va, vw, Ap, Wp, 32, K);
  __syncthreads();

  const int NPH = K >> 5;                  // 32 phases of BK=32
  for (int p = 0; p < NPH; ++p){
    const float (*ac)[128] = a_s[p & 1];
    const float (*wc)[128] = w_s[p & 1];
    if (p + 1 < NPH){
      // buf[(p+1)&1] was last read in phase p-1 (barrier passed) — safe.
      stage4(a_s[(p+1)&1], w_s[(p+1)&1], va, vw, srow, scol, swz);
      if (p + 2 < NPH) pref4(va, vw, Ap, Wp, (p+2)*32, K);
    }
    comp32(ac, wc, acc, tx, ty);
    __syncthreads();
  }

  float bias[8];
  #pragma unroll
  for (int j=0;j<8;j++) bias[j] = bia[n0 + tx*8 + j];
  #pragma unroll
  for (int i=0;i<8;i++){
    int row = m0 + ty*8 + i;
    float4 o0 = {acc[i][0]+bias[0], acc[i][1]+bias[1], acc[i][2]+bias[2], acc[i][3]+bias[3]};
    float4 o1 = {acc[i][4]+bias[4], acc[i][5]+bias[5], acc[i][6]+bias[6], acc[i][7]+bias[7]};
    *(float4*)(Cout + (size_t)row*ldc + n0 + tx*8)     = o0;
    *(float4*)(Cout + (size_t)row*ldc + n0 + tx*8 + 4) = o1;
  }
}

// ---------- bf16 MFMA GEMM (v-proj) — R6-validated ----------
#define BST 72
__global__ __launch_bounds__(256) void gemm_bf16_kernel(
    const float* __restrict__ A, const float* __restrict__ W,
    const float* __restrict__ bias, float* __restrict__ C,
    int K, int ldc)
{
  __shared__ unsigned short a_sh[128*BST];
  __shared__ unsigned short w_sh[128*BST];
  const int t = threadIdx.x;
  const int m0 = blockIdx.y * 128, n0 = blockIdx.x * 128;
  const int lane = t & 63, wid = t >> 6;
  const int mw = (wid >> 1) * 64, nw = (wid & 1) * 64;
  const int lr = lane & 15, lg = lane >> 4;

  f32x4 acc[4][4];
  #pragma unroll
  for (int i=0;i<4;i++)
    #pragma unroll
    for (int j=0;j<4;j++) acc[i][j] = (f32x4){0.f,0.f,0.f,0.f};

  const int srow = t >> 3;
  const int scol = (t & 7) * 8;

  for (int kt = 0; kt < K; kt += 64){
    __syncthreads();
    #pragma unroll
    for (int ii = 0; ii < 4; ii++){
      int row = srow + ii*32;
      const float4 f0 = *(const float4*)(A + (size_t)(m0+row)*K + kt + scol);
      const float4 f1 = *(const float4*)(A + (size_t)(m0+row)*K + kt + scol + 4);
      uint4 ua = { bpack2(f0.x,f0.y), bpack2(f0.z,f0.w), bpack2(f1.x,f1.y), bpack2(f1.z,f1.w) };
      *(uint4*)&a_sh[row*BST + scol] = ua;
      const float4 g0 = *(const float4*)(W + (size_t)(n0+row)*K + kt + scol);
      const float4 g1 = *(const float4*)(W + (size_t)(n0+row)*K + kt + scol + 4);
      uint4 uw = { bpack2(g0.x,g0.y), bpack2(g0.z,g0.w), bpack2(g1.x,g1.y), bpack2(g1.z,g1.w) };
      *(uint4*)&w_sh[row*BST + scol] = uw;
    }
    __syncthreads();
    #pragma unroll
    for (int ks = 0; ks < 64; ks += 32){
      short8 af[4], bw[4];
      #pragma unroll
      for (int i=0;i<4;i++) af[i] = *(const short8*)&a_sh[(mw + i*16 + lr)*BST + ks + lg*8];
      #pragma unroll
      for (int j=0;j<4;j++) bw[j] = *(const short8*)&w_sh[(nw + j*16 + lr)*BST + ks + lg*8];
      #pragma unroll
      for (int i=0;i<4;i++)
        #pragma unroll
        for (int j=0;j<4;j++)
          acc[i][j] = __builtin_amdgcn_mfma_f32_16x16x32_bf16(af[i], bw[j], acc[i][j], 0, 0, 0);
    }
  }
  #pragma unroll
  for (int j=0;j<4;j++){
    int col = n0 + nw + j*16 + lr;
    float bs = bias[col];
    #pragma unroll
    for (int i=0;i<4;i++){
      int rbase = m0 + mw + i*16 + lg*4;
      #pragma unroll
      for (int r=0;r<4;r++)
        C[(size_t)(rbase+r)*ldc + col] = acc[i][j][r] + bs;
    }
  }
}

// ---------- out-proj with fused round-combine in A-staging (R14) ----------
// Replaces combine_kernel + gemm_bf16(ocomb): stages A directly from
// o_r16 (bf16, both rounds) + lse. Per k-tile h = kt>>7 is constant, so
// each staged row needs 2 lse loads + 2 exp. The staged bf16 value is
// bf16_round(w0*x + w1*y) — the exact composition the combine->stage
// pair computed, so `out` is bit-identical. Saves one dispatch + 64MB
// of ocomb HBM round-trip.
__global__ __launch_bounds__(256) void gemm_out_kernel(
    const unsigned short* __restrict__ o_r16, const float* __restrict__ lse,
    const float* __restrict__ W, const float* __restrict__ bias,
    float* __restrict__ C)
{
  const int K = 1024, ldc = 1024;
  __shared__ unsigned short a_sh[128*BST];
  __shared__ unsigned short w_sh[128*BST];
  const int t = threadIdx.x;
  const int m0 = blockIdx.y * 128, n0 = blockIdx.x * 128;
  const int lane = t & 63, wid = t >> 6;
  const int mw = (wid >> 1) * 64, nw = (wid & 1) * 64;
  const int lr = lane & 15, lg = lane >> 4;

  f32x4 acc[4][4];
  #pragma unroll
  for (int i=0;i<4;i++)
    #pragma unroll
    for (int j=0;j<4;j++) acc[i][j] = (f32x4){0.f,0.f,0.f,0.f};

  const int srow = t >> 3;
  const int scol = (t & 7) * 8;

  for (int kt = 0; kt < K; kt += 64){
    __syncthreads();
    const int h = kt >> 7;
    const int dbase = (kt & 64) + scol;        // column within head, 0..120
    #pragma unroll
    for (int ii = 0; ii < 4; ii++){
      int row = srow + ii*32;
      // A-row = ocomb row (s*B+b); combine weights per (row, h)
      int grow = m0 + row;
      int s = grow >> 1, b = grow & 1;
      size_t i0 = (size_t)((b*2 + 0)*8 + h)*S_LEN + s;
      size_t i1 = (size_t)((b*2 + 1)*8 + h)*S_LEN + s;
      float l0 = lse[i0], l1 = lse[i1];
      float mm = fmaxf(l0,l1);
      float w0 = expf(l0-mm), w1 = expf(l1-mm);
      float inv = 1.0f/(w0+w1);
      w0*=inv; w1*=inv;
      const unsigned short* p0 = o_r16 + i0*128 + dbase;
      const unsigned short* p1 = o_r16 + i1*128 + dbase;
      uint4 u0 = *(const uint4*)p0;
      uint4 u1 = *(const uint4*)p1;
      float f[8];
      #pragma unroll
      for (int j=0;j<4;j++){
        unsigned av = ((const unsigned*)&u0)[j];
        unsigned cv = ((const unsigned*)&u1)[j];
        f[2*j]   = w0*bf2f((unsigned short)(av & 0xffff)) + w1*bf2f((unsigned short)(cv & 0xffff));
        f[2*j+1] = w0*bf2f((unsigned short)(av >> 16))    + w1*bf2f((unsigned short)(cv >> 16));
      }
      uint4 ua = { bpack2(f[0],f[1]), bpack2(f[2],f[3]), bpack2(f[4],f[5]), bpack2(f[6],f[7]) };
      *(uint4*)&a_sh[row*BST + scol] = ua;
      // W staging unchanged
      const float4 g0 = *(const float4*)(W + (size_t)(n0+row)*K + kt + scol);
      const float4 g1 = *(const float4*)(W + (size_t)(n0+row)*K + kt + scol + 4);
      uint4 uw = { bpack2(g0.x,g0.y), bpack2(g0.z,g0.w), bpack2(g1.x,g1.y), bpack2(g1.z,g1.w) };
      *(uint4*)&w_sh[row*BST + scol] = uw;
    }
    __syncthreads();
    #pragma unroll
    for (int ks = 0; ks < 64; ks += 32){
      short8 af[4], bw[4];
      #pragma unroll
      for (int i=0;i<4;i++) af[i] = *(const short8*)&a_sh[(mw + i*16 + lr)*BST + ks + lg*8];
      #pragma unroll
      for (int j=0;j<4;j++) bw[j] = *(const short8*)&w_sh[(nw + j*16 + lr)*BST + ks + lg*8];
      #pragma unroll
      for (int i=0;i<4;i++)
        #pragma unroll
        for (int j=0;j<4;j++)
          acc[i][j] = __builtin_amdgcn_mfma_f32_16x16x32_bf16(af[i], bw[j], acc[i][j], 0, 0, 0);
    }
  }
  #pragma unroll
  for (int j=0;j<4;j++){
    int col = n0 + nw + j*16 + lr;
    float bs = bias[col];
    #pragma unroll
    for (int i=0;i<4;i++){
      int rbase = m0 + mw + i*16 + lg*4;
      #pragma unroll
      for (int r=0;r<4;r++)
        C[(size_t)(rbase+r)*ldc + col] = acc[i][j][r] + bs;
    }
  }
}

// ---------- per-row norm over E ----------
__global__ __launch_bounds__(256) void invnorm_kernel(const float* __restrict__ qv,
                                                      float* __restrict__ invn,
                                                      float* __restrict__ nrm)
{
  int row = blockIdx.x;
  int t = threadIdx.x;
  float4 v = *(const float4*)(qv + (size_t)row*QV_STRIDE + t*4);
  float ss = v.x*v.x + v.y*v.y + v.z*v.z + v.w*v.w;
  #pragma unroll
  for (int off=32; off; off>>=1) ss += __shfl_down(ss, off);
  __shared__ float part[4];
  if ((t & 63)==0) part[t>>6] = ss;
  __syncthreads();
  if (t==0){
    float n = sqrtf(part[0]+part[1]+part[2]+part[3]);
    nrm[row]  = n;
    invn[row] = 1.0f/n;
  }
}

// ---------- fp32 hash path, reference-order mimicry (R5 pass; DO NOT TOUCH) ----------
__global__ __launch_bounds__(256) void hash32_kernel(
    const float* __restrict__ qv, const float* __restrict__ nrm,
    const float* __restrict__ hw, int* __restrict__ hashes)
{
  int idx = blockIdx.x*256 + threadIdx.x;
  int s = idx & (S_LEN-1);
  int h = (idx >> 12) & 7;
  int r = (idx >> 15) & 1;
  int b = idx >> 16;
  const float* qr = qv + (size_t)(s*B_SZ + b)*QV_STRIDE + h*D_HEAD;
  const float  n  = nrm[s*B_SZ + b];
  const float* wp = hw + (size_t)(r*H_HEADS + h)*D_HEAD*8;
  float lin[8];
  #pragma unroll
  for (int m=0;m<8;m++) lin[m]=0.f;
  for (int d=0; d<D_HEAD; d++){
    float kd = qr[d] / n;
    #pragma unroll
    for (int m=0;m<8;m++) lin[m] = fmaf(kd, wp[d*8+m], lin[m]);
  }
  float best = lin[0]; int bi = 0;
  #pragma unroll
  for (int m=1;m<8;m++) if (lin[m] > best){ best=lin[m]; bi=m; }
  #pragma unroll
  for (int m=0;m<8;m++) if (-lin[m] > best){ best=-lin[m]; bi=8+m; }
  hashes[idx] = bi;
}

// ---------- stable counting sort by bucket, per (b,r,h) ----------
__global__ __launch_bounds__(256) void sort_kernel(const int* __restrict__ hashes,
                                                   int* __restrict__ sidx,
                                                   unsigned short* __restrict__ hs_pack)
{
  __shared__ unsigned char bucket_s[S_LEN];
  __shared__ int counts[16][257];
  __shared__ int bbase[16];
  int t = threadIdx.x;
  size_t base = (size_t)blockIdx.x * S_LEN;
  for (int e=0;e<16;e++) bucket_s[t + e*256] = (unsigned char)hashes[base + t + e*256];
  #pragma unroll
  for (int u=0;u<16;u++) counts[u][t]=0;
  if (t<16) counts[t][256]=0;
  __syncthreads();
  int s0 = t*16;
  for (int e=0;e<16;e++){ int u = bucket_s[s0+e]; counts[u][t]++; }
  __syncthreads();
  if (t < 16){
    int run=0;
    for (int tt=0; tt<256; tt++){ int c = counts[t][tt]; counts[t][tt]=run; run+=c; }
    counts[t][256]=run;
  }
  __syncthreads();
  if (t==0){
    int run=0;
    for (int u=0;u<16;u++){ bbase[u]=run; run += counts[u][256]; }
  }
  __syncthreads();
  for (int e=0;e<16;e++){
    int s = s0+e; int u = bucket_s[s];
    int pos = bbase[u] + counts[u][t]; counts[u][t]++;
    sidx[base+pos] = s;
    hs_pack[base+pos] = (unsigned short)(s | (u<<12));
  }
}

// ---------- gather: sorted bf16 K-hat rows + transposed V ----------
// ksort[brh][pos][d]  = q[token][h,d] * invn[token]   (bf16)
// vsortT[brh][d][pos] = v[token][h,d]                 (bf16, transposed in LDS)
#define GST 136
__global__ __launch_bounds__(256) void gather_kernel(
    const float* __restrict__ qv, const float* __restrict__ invn,
    const int* __restrict__ sidx,
    unsigned short* __restrict__ ksort, unsigned short* __restrict__ vsortT)
{
  __shared__ int tok_s[256];
  __shared__ float sc_s[256];
  __shared__ unsigned short v_sub[64*GST];
  const int t = threadIdx.x;
  const int brh = blockIdx.x >> 4, pc = blockIdx.x & 15;
  const int b = brh >> 4;
  const int h = brh & 7;
  const size_t base_s = (size_t)brh * S_LEN;
  const int pos0 = pc * 256;
  {
    int tok = sidx[base_s + pos0 + t];
    tok_s[t] = tok;
    sc_s[t] = invn[tok*B_SZ + b];
  }
  __syncthreads();
  // ksort: coalesced row-major bf16
  #pragma unroll 4
  for (int i=0;i<16;i++){
    int slot = i*256 + t;
    int pos = slot >> 4, g = slot & 15;
    int tok = tok_s[pos]; float sc = sc_s[pos];
    const float* src = qv + ((size_t)tok*B_SZ + b)*QV_STRIDE + h*D_HEAD + g*8;
    float4 f0 = *(const float4*)src, f1 = *(const float4*)(src+4);
    uint4 u = { bpack2(f0.x*sc, f0.y*sc), bpack2(f0.z*sc, f0.w*sc),
                bpack2(f1.x*sc, f1.y*sc), bpack2(f1.z*sc, f1.w*sc) };
    *(uint4*)&ksort[(base_s + pos0 + pos)*128 + g*8] = u;
  }
  // vsortT: 4 sub-tiles of 64 pos, LDS transpose
  for (int sub=0; sub<4; sub++){
    __syncthreads();
    #pragma unroll
    for (int i=0;i<4;i++){
      int slot = i*256 + t;
      int pr = slot >> 4, g = slot & 15;
      int tok = tok_s[sub*64 + pr];
      const float* src = qv + ((size_t)tok*B_SZ + b)*QV_STRIDE + 1024 + h*D_HEAD + g*8;
      float4 f0 = *(const float4*)src, f1 = *(const float4*)(src+4);
      uint4 u = { bpack2(f0.x,f0.y), bpack2(f0.z,f0.w), bpack2(f1.x,f1.y), bpack2(f1.z,f1.w) };
      *(uint4*)&v_sub[pr*GST + g*8] = u;
    }
    __syncthreads();
    #pragma unroll
    for (int i=0;i<8;i++){
      int oslot = i*256 + t;             // 2048 = 128 d x 16 pos-groups
      int d = oslot >> 4, p4 = (oslot & 15)*4;
      unsigned a0 = v_sub[(p4+0)*GST + d];
      unsigned a1 = v_sub[(p4+1)*GST + d];
      unsigned a2 = v_sub[(p4+2)*GST + d];
      unsigned a3 = v_sub[(p4+3)*GST + d];
      uint2 o = { a0 | (a1<<16), a2 | (a3<<16) };
      *(uint2*)&vsortT[(size_t)brh*524288 + (size_t)d*4096 + pos0 + sub*64 + p4] = o;
    }
  }
}

// ---------- MFMA chunked LSH attention ----------
// Reference quirk (silent broadcast): for query at sorted position p=n*64+c,
// scores/values use win(n), but BOTH masks compare vs win(c).
// S rows post-scaled by SCALE*nrm[token] (Q = k-hat * SCALE*nrm exactly up to
// smooth fp noise). Full 192-wide softmax in registers; P via LDS (bf16).
#define KST 136
#define VST 72
#define PST 200
__device__ inline int swzg(int row, int g){ return (g ^ (row & 7)) << 3; }

__global__ __launch_bounds__(256) void attn_mfma_kernel(
    const unsigned short* __restrict__ ksort, const unsigned short* __restrict__ vsortT,
    const float* __restrict__ nrm, const unsigned short* __restrict__ hs_pack,
    unsigned short* __restrict__ o_r16, float* __restrict__ lse_g)
{
  __shared__ unsigned short kv_un[128*VST];          // 9216 u16: K chunk (64x136) or V^T chunk (128x72)
  __shared__ unsigned short p_sh[64*PST];
  __shared__ __align__(16) unsigned short pack_s[S_LEN];
  __shared__ float srow_s[64];

  const int t = threadIdx.x;
  const int bid = blockIdx.x;
  const int nc = bid & 63;
  const int brh = bid >> 6;
  const int b = brh >> 4;
  const size_t base_s = (size_t)brh * S_LEN;

  {
    const uint4* src = (const uint4*)(hs_pack + base_s);
    uint4* dst = (uint4*)pack_s;
    dst[t]       = src[t];
    dst[256 + t] = src[256 + t];
  }
  __syncthreads();
  if (t < 64){
    int tok = pack_s[nc*64 + t] & 0xfff;
    srow_s[t] = SCALE_F * nrm[tok*B_SZ + b];
  }

  const int lane = t & 63, wid = t >> 6;
  const int mw = wid * 16;                 // wave's 16 query rows
  const int lr = lane & 15, lg = lane >> 4;

  f32x4 acc[12];
  #pragma unroll
  for (int i=0;i<12;i++) acc[i] = (f32x4){0.f,0.f,0.f,0.f};
  short8 aq[4];

  // ---- QK^T: window chunks, w=1 first (supplies Q fragments) ----
  const int worder[3] = {1, 0, 2};
  #pragma unroll
  for (int wi=0; wi<3; wi++){
    int w = worder[wi];
    int cwch = (nc + w + 63) & 63;
    __syncthreads();                       // also covers srow_s on first iter
    #pragma unroll
    for (int i=0;i<4;i++){
      int slot = i*256 + t;
      int row = slot >> 4, g = slot & 15;
      uint4 u = *(const uint4*)&ksort[(base_s + cwch*64 + row)*128 + g*8];
      *(uint4*)&kv_un[row*KST + swzg(row, g)] = u;
    }
    __syncthreads();
    if (wi==0){
      #pragma unroll
      for (int ks=0; ks<4; ks++)
        aq[ks] = *(const short8*)&kv_un[(mw+lr)*KST + swzg(mw+lr, ks*4+lg)];
    }
    #pragma unroll
    for (int ks=0; ks<4; ks++){
      #pragma unroll
      for (int k4=0; k4<4; k4++){
        short8 bk = *(const short8*)&kv_un[(k4*16+lr)*KST + swzg(k4*16+lr, ks*4+lg)];
        acc[w*4+k4] = __builtin_amdgcn_mfma_f32_16x16x32_bf16(aq[ks], bk, acc[w*4+k4], 0,0,0);
      }
    }
  }

  // ---- scale + masks + softmax (C-layout: col=lr, rows mw+lg*4+r) ----
  unsigned pq[4]; float sr[4]; int c_[4]; float linv[4];
  #pragma unroll
  for (int r=0;r<4;r++){
    c_[r] = mw + lg*4 + r;
    pq[r] = pack_s[nc*64 + c_[r]];
    sr[r] = srow_s[c_[r]];
  }
  #pragma unroll
  for (int ti=0; ti<12; ti++){
    int w = ti >> 2, k4 = ti & 3;
    #pragma unroll
    for (int r=0;r<4;r++){
      int mc = (c_[r] + w + 63) & 63;
      unsigned e = pack_s[mc*64 + k4*16 + lr];
      float s = acc[ti][r] * sr[r];
      s = ((e>>12) == (pq[r]>>12)) ? s : NEG_F;
      if ((e & 0xfffu) == (pq[r] & 0xfffu)) s = NEG_SELF_F;
      acc[ti][r] = s;
    }
  }
  #pragma unroll
  for (int r=0;r<4;r++){
    float m = acc[0][r];
    #pragma unroll
    for (int ti=1; ti<12; ti++) m = fmaxf(m, acc[ti][r]);
    #pragma unroll
    for (int off=1; off<16; off<<=1) m = fmaxf(m, __shfl_xor(m, off));
    float l = 0.f;
    #pragma unroll
    for (int ti=0; ti<12; ti++){
      float p = __expf(acc[ti][r] - m);
      l += p;
      int wpos = (ti>>2)*64 + (ti&3)*16 + lr;
      p_sh[c_[r]*PST + (((wpos>>3) ^ (c_[r]&7))<<3) + (wpos&7)] = (unsigned short)bfr(p);
    }
    #pragma unroll
    for (int off=1; off<16; off<<=1) l += __shfl_xor(l, off);
    linv[r] = 1.0f / l;
    if (lr == 0) lse_g[base_s + (pq[r] & 0xfffu)] = m + logf(l);
  }

  // ---- PV ----
  f32x4 oacc[8];
  #pragma unroll
  for (int i=0;i<8;i++) oacc[i] = (f32x4){0.f,0.f,0.f,0.f};
  for (int w=0; w<3; w++){
    int cwch = (nc + w + 63) & 63;
    __syncthreads();                       // p_sh written; kv_un free
    #pragma unroll
    for (int i=0;i<4;i++){
      int slot = i*256 + t;                // 1024 = 128 d x 8 key-groups
      int d = slot >> 3, kg = slot & 7;
      uint4 u = *(const uint4*)&vsortT[(size_t)brh*524288 + (size_t)d*4096 + cwch*64 + kg*8];
      *(uint4*)&kv_un[d*VST + swzg(d, kg)] = u;
    }
    __syncthreads();
    short8 ap[2];
    #pragma unroll
    for (int ks=0; ks<2; ks++){
      int g = w*8 + ks*4 + lg;
      ap[ks] = *(const short8*)&p_sh[(mw+lr)*PST + ((g ^ ((mw+lr)&7))<<3)];
    }
    #pragma unroll
    for (int ks=0; ks<2; ks++)
      #pragma unroll
      for (int dt=0; dt<8; dt++){
        short8 bv = *(const short8*)&kv_un[(dt*16+lr)*VST + swzg(dt*16+lr, ks*4+lg)];
        oacc[dt] = __builtin_amdgcn_mfma_f32_16x16x32_bf16(ap[ks], bv, oacc[dt], 0,0,0);
      }
  }

  // ---- epilogue: bf16 scatter by token ----
  #pragma unroll
  for (int r=0;r<4;r++){
    int tok = pq[r] & 0xfff;
    size_t ob = (base_s + tok) * 128;
    #pragma unroll
    for (int dt=0; dt<8; dt++)
      o_r16[ob + dt*16 + lr] = (unsigned short)bfr(oacc[dt][r] * linv[r]);
  }
}

// ---------- launch ----------
extern "C" void kernel_launch(void* const* d_in, const int* in_sizes, int n_in,
                              void* d_out, int out_size, void* d_ws, size_t ws_size,
                              hipStream_t stream)
{
  (void)in_sizes; (void)n_in; (void)out_size; (void)ws_size;
  const float* x  = (const float*)d_in[0];
  const float* wq = (const float*)d_in[1];
  const float* bq = (const float*)d_in[2];
  const float* wv = (const float*)d_in[3];
  const float* bv = (const float*)d_in[4];
  const float* wo = (const float*)d_in[5];
  const float* bo = (const float*)d_in[6];
  const float* hw = (const float*)d_in[7];
  float* out = (float*)d_out;

  float* ws    = (float*)d_ws;
  float* qv    = ws;                          // [8192][2048] q|v fp32
  float* invn  = ws + 16777216;               // [8192]
  float* nrm   = ws + 16785408;               // [8192]
  int*   hashes= (int*)(ws + 16793600);       // [B,R,H,S]
  int*   sidx  = (int*)(ws + 16924672);       // [B,R,H,S]
  float* lse   = ws + 17055744;               // [B,R,H,S]
  unsigned short* o_r16   = (unsigned short*)(ws + 17186816);  // [32][4096][128] bf16
  unsigned short* ksort   = (unsigned short*)(ws + 25575424);  // [32][4096][128] bf16
  unsigned short* vsortT  = (unsigned short*)(ws + 33964032);  // [32][128][4096] bf16
  unsigned short* hs_pack = (unsigned short*)(ws + 42352640);  // [B,R,H,S] packed

  gemm_f32_kernel<<<dim3(8,64), 256, 0, stream>>>(x, wq, bq, qv, 1024, 1024, QV_STRIDE);
  gemm_bf16_kernel<<<dim3(8,64), 256, 0, stream>>>(x, wv, bv, qv + 1024, 1024, QV_STRIDE);
  invnorm_kernel<<<dim3(8192), 256, 0, stream>>>(qv, invn, nrm);
  hash32_kernel<<<dim3(512), 256, 0, stream>>>(qv, nrm, hw, hashes);
  sort_kernel<<<dim3(32), 256, 0, stream>>>(hashes, sidx, hs_pack);
  gather_kernel<<<dim3(512), 256, 0, stream>>>(qv, invn, sidx, ksort, vsortT);
  attn_mfma_kernel<<<dim3(2048), 256, 0, stream>>>(ksort, vsortT, nrm, hs_pack, o_r16, lse);
  gemm_out_kernel<<<dim3(8,64), 256, 0, stream>>>(o_r16, lse, wo, bo, out);
}

// Round 11
// 504.299 us; speedup vs baseline: 1.4982x; 1.1882x over previous
//
#include <hip/hip_runtime.h>
#include <hip/hip_bf16.h>
#include <math.h>

// Problem dims
#define S_LEN   4096
#define B_SZ    2
#define E_DIM   1024
#define H_HEADS 8
#define R_ROUNDS 2
#define C_CHUNK 64
#define D_HEAD  128
#define NC_CHUNKS 64
#define QV_STRIDE 2048              // q (1024) | v (1024) per row
#define SCALE_F 0.08838834764831845f
#define NEG_F (-1e9f)
#define NEG_SELF_F (-1e5f)

typedef __attribute__((ext_vector_type(8))) short short8;
typedef __attribute__((ext_vector_type(4))) float f32x4;

// fp32 -> bf16 (RNE) bit pattern
__device__ inline unsigned bfr(float x){
  unsigned u = __float_as_uint(x);
  return (u + 0x7fffu + ((u >> 16) & 1u)) >> 16;
}
__device__ inline unsigned bpack2(float a, float b){ return bfr(a) | (bfr(b) << 16); }
__device__ inline float bf2f(unsigned short v){ return __uint_as_float((unsigned)v << 16); }

// async global->LDS 16B copy (wave-uniform LDS base + lane*16 semantics)
__device__ inline void gl_lds16(const void* g, void* l){
  __builtin_amdgcn_global_load_lds((const __attribute__((address_space(1))) unsigned*)g,
                                   (__attribute__((address_space(3))) unsigned*)l, 16, 0, 0);
}

// LDS column remap for 128-wide fp32 GEMM tiles
__device__ inline int sm_col(int c){ return ((c & 4) << 4) | ((c >> 3) << 2) | (c & 3); }

// ---------- fp32 tiled GEMM (q projection ONLY) — R2-best, 219.5us ----------
// Single fp32 FMA chain per output, k ascending — mirrors CPU sgemm so q
// feeding the discrete hash argmax matches reference rounding.
// CHAIN ORDER IS SACRED. History: R7 swizzle (12.6M conflicts -> 0, 220us);
// R8 dbuf (neutral, kept); R9-R12 global-A / 16x8-tile / R13 fusion ALL
// regressed. The LDS-return-path wall (8 waves x 4 ds_read_b128 x 12cy =
// 384cy vs 256cy FMA per CU per kk = 66% VALUBusy) is this kernel's
// practical floor at this grid geometry. PARKED.
__device__ inline void pref4(float4 (&va)[4], float4 (&vw)[4],
                             const float* __restrict__ Ap, const float* __restrict__ Wp,
                             int kt, int K){
  #pragma unroll
  for (int ii=0; ii<4; ii++){
    va[ii] = *(const float4*)(Ap + kt + (size_t)ii*32*K);
    vw[ii] = *(const float4*)(Wp + kt + (size_t)ii*32*K);
  }
}

__device__ inline void stage4(float (*a_s)[128], float (*w_s)[128],
                              const float4 (&va)[4], const float4 (&vw)[4],
                              int srow, int scol, int swz){
  #pragma unroll
  for (int ii=0; ii<4; ii++){
    int cp = sm_col(srow + ii*32) ^ swz;   // swz = (t&7)<<2 == f(scol+j) for j=0..3
    a_s[scol+0][cp]=va[ii].x; a_s[scol+1][cp]=va[ii].y; a_s[scol+2][cp]=va[ii].z; a_s[scol+3][cp]=va[ii].w;
    w_s[scol+0][cp]=vw[ii].x; w_s[scol+1][cp]=vw[ii].y; w_s[scol+2][cp]=vw[ii].z; w_s[scol+3][cp]=vw[ii].w;
  }
}

__device__ inline void comp32(const float (*a_s)[128], const float (*w_s)[128],
                              float (&acc)[8][8], int tx, int ty){
  #pragma unroll 4
  for (int kk=0; kk<32; kk++){
    int fk = ((kk>>2)&7)<<2;               // must match store-side swizzle
    int ca = (ty*4) ^ fk;
    int cw = (tx*4) ^ fk;
    float4 a0  = *(const float4*)&a_s[kk][ca];
    float4 a1  = *(const float4*)&a_s[kk][64+ca];
    float4 w0v = *(const float4*)&w_s[kk][cw];
    float4 w1v = *(const float4*)&w_s[kk][64+cw];
    float am[8] = {a0.x,a0.y,a0.z,a0.w,a1.x,a1.y,a1.z,a1.w};
    float wm[8] = {w0v.x,w0v.y,w0v.z,w0v.w,w1v.x,w1v.y,w1v.z,w1v.w};
    #pragma unroll
    for (int i=0;i<8;i++)
      #pragma unroll
      for (int j=0;j<8;j++)
        acc[i][j] = fmaf(am[i], wm[j], acc[i][j]);
  }
}

__global__ __launch_bounds__(256) void gemm_f32_kernel(
    const float* __restrict__ A, const float* __restrict__ W, const float* __restrict__ bia,
    float* __restrict__ Cout, int N, int K, int ldc)
{
  __shared__ __align__(16) float a_s[2][32][128];
  __shared__ __align__(16) float w_s[2][32][128];
  const int t  = threadIdx.x;
  const int n0 = blockIdx.x * 128;
  const int m0 = blockIdx.y * 128;
  const int tx = t & 15, ty = t >> 4;

  float acc[8][8];
  #pragma unroll
  for (int i=0;i<8;i++)
    #pragma unroll
    for (int j=0;j<8;j++) acc[i][j]=0.f;

  const int srow = t >> 3;
  const int scol = (t & 7) * 4;
  const int swz  = (t & 7) << 2;

  const float* Ap = A + (size_t)(m0 + srow)*K + scol;
  const float* Wp = W + (size_t)(n0 + srow)*K + scol;

  float4 va[4], vw[4];
  pref4(va, vw, Ap, Wp, 0, K);
  stage4(a_s[0], w_s[0], va, vw, srow, scol, swz);
  pref4(va, vw, Ap, Wp, 32, K);
  __syncthreads();

  const int NPH = K >> 5;                  // 32 phases of BK=32
  for (int p = 0; p < NPH; ++p){
    const float (*ac)[128] = a_s[p & 1];
    const float (*wc)[128] = w_s[p & 1];
    if (p + 1 < NPH){
      // buf[(p+1)&1] was last read in phase p-1 (barrier passed) — safe.
      stage4(a_s[(p+1)&1], w_s[(p+1)&1], va, vw, srow, scol, swz);
      if (p + 2 < NPH) pref4(va, vw, Ap, Wp, (p+2)*32, K);
    }
    comp32(ac, wc, acc, tx, ty);
    __syncthreads();
  }

  float bias[8];
  #pragma unroll
  for (int j=0;j<8;j++) bias[j] = bia[n0 + tx*8 + j];
  #pragma unroll
  for (int i=0;i<8;i++){
    int row = m0 + ty*8 + i;
    float4 o0 = {acc[i][0]+bias[0], acc[i][1]+bias[1], acc[i][2]+bias[2], acc[i][3]+bias[3]};
    float4 o1 = {acc[i][4]+bias[4], acc[i][5]+bias[5], acc[i][6]+bias[6], acc[i][7]+bias[7]};
    *(float4*)(Cout + (size_t)row*ldc + n0 + tx*8)     = o0;
    *(float4*)(Cout + (size_t)row*ldc + n0 + tx*8 + 4) = o1;
  }
}

// ---------- elementwise f32 -> bf16 (RNE, identical bits to bpack2) ----------
__global__ __launch_bounds__(256) void cvt_bf16_kernel(const float* __restrict__ src,
                                                       unsigned short* __restrict__ dst,
                                                       int n8)
{
  int i = blockIdx.x*256 + threadIdx.x;
  if (i < n8){
    const float4 f0 = *(const float4*)(src + (size_t)i*8);
    const float4 f1 = *(const float4*)(src + (size_t)i*8 + 4);
    uint4 u = { bpack2(f0.x,f0.y), bpack2(f0.z,f0.w), bpack2(f1.x,f1.y), bpack2(f1.z,f1.w) };
    *(uint4*)(dst + (size_t)i*8) = u;
  }
}

// ---------- v-proj: pure-bf16 GEMM with global_load_lds staging (R15) ----------
// Inputs pre-converted to bf16 (identical RNE bits to the old in-staging
// bpack2) -> staging is a raw copy: 8 global_load_lds(16B)/thread/tile,
// ZERO staging VALU. XOR col-group swizzle per rule #21: linear LDS dest,
// inverse-swizzled GLOBAL source, swizzled read -> conflict-free b128
// fragment reads. MFMA inputs bit-identical to R14's v-proj.
__global__ __launch_bounds__(256) void gemm_bf16gl_kernel(
    const unsigned short* __restrict__ A16, const unsigned short* __restrict__ W16,
    const float* __restrict__ bias, float* __restrict__ C,
    int K, int ldc)
{
  __shared__ __align__(16) unsigned short a_sh[128*64];
  __shared__ __align__(16) unsigned short w_sh[128*64];
  const int t = threadIdx.x;
  const int m0 = blockIdx.y * 128, n0 = blockIdx.x * 128;
  const int lane = t & 63, wid = t >> 6;
  const int mw = (wid >> 1) * 64, nw = (wid & 1) * 64;
  const int lr = lane & 15, lg = lane >> 4;

  f32x4 acc[4][4];
  #pragma unroll
  for (int i=0;i<4;i++)
    #pragma unroll
    for (int j=0;j<4;j++) acc[i][j] = (f32x4){0.f,0.f,0.f,0.f};

  // staging map: slot s = i*256+t -> row = s>>3 (=srow0+i*32), col-group s&7
  // LDS(row,u) holds global col-group u ^ (row&7)  (inverse-swz source)
  const int srow0 = t >> 3;
  const int swzr  = srow0 & 7;               // == row&7 for all i (i*32 % 8 == 0)
  const int gc8   = (t & 7) ^ swzr;          // global col-group fetched into slot t&7
  const int rsw   = lr & 7;                  // read-side row&7 (mw,i*16 are mult of 8)

  for (int kt = 0; kt < K; kt += 64){
    __syncthreads();
    #pragma unroll
    for (int i=0;i<4;i++){
      int row = srow0 + i*32;
      gl_lds16(A16 + (size_t)(m0+row)*K + kt + gc8*8, &a_sh[((size_t)i*256 + t)*8]);
      gl_lds16(W16 + (size_t)(n0+row)*K + kt + gc8*8, &w_sh[((size_t)i*256 + t)*8]);
    }
    __syncthreads();                        // compiler drains vmcnt here
    #pragma unroll
    for (int ks = 0; ks < 64; ks += 32){
      const int cg = (ks >> 3) + lg;        // col-group this fragment needs
      const int sl = (cg ^ rsw) * 8;        // swizzled LDS slot offset (elems)
      short8 af[4], bw[4];
      #pragma unroll
      for (int i=0;i<4;i++) af[i] = *(const short8*)&a_sh[(mw + i*16 + lr)*64 + sl];
      #pragma unroll
      for (int j=0;j<4;j++) bw[j] = *(const short8*)&w_sh[(nw + j*16 + lr)*64 + sl];
      #pragma unroll
      for (int i=0;i<4;i++)
        #pragma unroll
        for (int j=0;j<4;j++)
          acc[i][j] = __builtin_amdgcn_mfma_f32_16x16x32_bf16(af[i], bw[j], acc[i][j], 0, 0, 0);
    }
  }
  #pragma unroll
  for (int j=0;j<4;j++){
    int col = n0 + nw + j*16 + lr;
    float bs = bias[col];
    #pragma unroll
    for (int i=0;i<4;i++){
      int rbase = m0 + mw + i*16 + lg*4;
      #pragma unroll
      for (int r=0;r<4;r++)
        C[(size_t)(rbase+r)*ldc + col] = acc[i][j][r] + bs;
    }
  }
}

// ---------- out-proj with fused round-combine in A-staging (R14-validated) ----------
#define BST 72
__global__ __launch_bounds__(256) void gemm_out_kernel(
    const unsigned short* __restrict__ o_r16, const float* __restrict__ lse,
    const float* __restrict__ W, const float* __restrict__ bias,
    float* __restrict__ C)
{
  const int K = 1024, ldc = 1024;
  __shared__ unsigned short a_sh[128*BST];
  __shared__ unsigned short w_sh[128*BST];
  const int t = threadIdx.x;
  const int m0 = blockIdx.y * 128, n0 = blockIdx.x * 128;
  const int lane = t & 63, wid = t >> 6;
  const int mw = (wid >> 1) * 64, nw = (wid & 1) * 64;
  const int lr = lane & 15, lg = lane >> 4;

  f32x4 acc[4][4];
  #pragma unroll
  for (int i=0;i<4;i++)
    #pragma unroll
    for (int j=0;j<4;j++) acc[i][j] = (f32x4){0.f,0.f,0.f,0.f};

  const int srow = t >> 3;
  const int scol = (t & 7) * 8;

  for (int kt = 0; kt < K; kt += 64){
    __syncthreads();
    const int h = kt >> 7;
    const int dbase = (kt & 64) + scol;        // column within head, 0..120
    #pragma unroll
    for (int ii = 0; ii < 4; ii++){
      int row = srow + ii*32;
      int grow = m0 + row;
      int s = grow >> 1, b = grow & 1;
      size_t i0 = (size_t)((b*2 + 0)*8 + h)*S_LEN + s;
      size_t i1 = (size_t)((b*2 + 1)*8 + h)*S_LEN + s;
      float l0 = lse[i0], l1 = lse[i1];
      float mm = fmaxf(l0,l1);
      float w0 = expf(l0-mm), w1 = expf(l1-mm);
      float inv = 1.0f/(w0+w1);
      w0*=inv; w1*=inv;
      const unsigned short* p0 = o_r16 + i0*128 + dbase;
      const unsigned short* p1 = o_r16 + i1*128 + dbase;
      uint4 u0 = *(const uint4*)p0;
      uint4 u1 = *(const uint4*)p1;
      float f[8];
      #pragma unroll
      for (int j=0;j<4;j++){
        unsigned av = ((const unsigned*)&u0)[j];
        unsigned cv = ((const unsigned*)&u1)[j];
        f[2*j]   = w0*bf2f((unsigned short)(av & 0xffff)) + w1*bf2f((unsigned short)(cv & 0xffff));
        f[2*j+1] = w0*bf2f((unsigned short)(av >> 16))    + w1*bf2f((unsigned short)(cv >> 16));
      }
      uint4 ua = { bpack2(f[0],f[1]), bpack2(f[2],f[3]), bpack2(f[4],f[5]), bpack2(f[6],f[7]) };
      *(uint4*)&a_sh[row*BST + scol] = ua;
      const float4 g0 = *(const float4*)(W + (size_t)(n0+row)*K + kt + scol);
      const float4 g1 = *(const float4*)(W + (size_t)(n0+row)*K + kt + scol + 4);
      uint4 uw = { bpack2(g0.x,g0.y), bpack2(g0.z,g0.w), bpack2(g1.x,g1.y), bpack2(g1.z,g1.w) };
      *(uint4*)&w_sh[row*BST + scol] = uw;
    }
    __syncthreads();
    #pragma unroll
    for (int ks = 0; ks < 64; ks += 32){
      short8 af[4], bw[4];
      #pragma unroll
      for (int i=0;i<4;i++) af[i] = *(const short8*)&a_sh[(mw + i*16 + lr)*BST + ks + lg*8];
      #pragma unroll
      for (int j=0;j<4;j++) bw[j] = *(const short8*)&w_sh[(nw + j*16 + lr)*BST + ks + lg*8];
      #pragma unroll
      for (int i=0;i<4;i++)
        #pragma unroll
        for (int j=0;j<4;j++)
          acc[i][j] = __builtin_amdgcn_mfma_f32_16x16x32_bf16(af[i], bw[j], acc[i][j], 0, 0, 0);
    }
  }
  #pragma unroll
  for (int j=0;j<4;j++){
    int col = n0 + nw + j*16 + lr;
    float bs = bias[col];
    #pragma unroll
    for (int i=0;i<4;i++){
      int rbase = m0 + mw + i*16 + lg*4;
      #pragma unroll
      for (int r=0;r<4;r++)
        C[(size_t)(rbase+r)*ldc + col] = acc[i][j][r] + bs;
    }
  }
}

// ---------- per-row norm over E ----------
__global__ __launch_bounds__(256) void invnorm_kernel(const float* __restrict__ qv,
                                                      float* __restrict__ invn,
                                                      float* __restrict__ nrm)
{
  int row = blockIdx.x;
  int t = threadIdx.x;
  float4 v = *(const float4*)(qv + (size_t)row*QV_STRIDE + t*4);
  float ss = v.x*v.x + v.y*v.y + v.z*v.z + v.w*v.w;
  #pragma unroll
  for (int off=32; off; off>>=1) ss += __shfl_down(ss, off);
  __shared__ float part[4];
  if ((t & 63)==0) part[t>>6] = ss;
  __syncthreads();
  if (t==0){
    float n = sqrtf(part[0]+part[1]+part[2]+part[3]);
    nrm[row]  = n;
    invn[row] = 1.0f/n;
  }
}

// ---------- fp32 hash path, reference-order mimicry (R5 pass; DO NOT TOUCH) ----------
__global__ __launch_bounds__(256) void hash32_kernel(
    const float* __restrict__ qv, const float* __restrict__ nrm,
    const float* __restrict__ hw, int* __restrict__ hashes)
{
  int idx = blockIdx.x*256 + threadIdx.x;
  int s = idx & (S_LEN-1);
  int h = (idx >> 12) & 7;
  int r = (idx >> 15) & 1;
  int b = idx >> 16;
  const float* qr = qv + (size_t)(s*B_SZ + b)*QV_STRIDE + h*D_HEAD;
  const float  n  = nrm[s*B_SZ + b];
  const float* wp = hw + (size_t)(r*H_HEADS + h)*D_HEAD*8;
  float lin[8];
  #pragma unroll
  for (int m=0;m<8;m++) lin[m]=0.f;
  for (int d=0; d<D_HEAD; d++){
    float kd = qr[d] / n;
    #pragma unroll
    for (int m=0;m<8;m++) lin[m] = fmaf(kd, wp[d*8+m], lin[m]);
  }
  float best = lin[0]; int bi = 0;
  #pragma unroll
  for (int m=1;m<8;m++) if (lin[m] > best){ best=lin[m]; bi=m; }
  #pragma unroll
  for (int m=0;m<8;m++) if (-lin[m] > best){ best=-lin[m]; bi=8+m; }
  hashes[idx] = bi;
}

// ---------- stable counting sort by bucket, per (b,r,h) ----------
__global__ __launch_bounds__(256) void sort_kernel(const int* __restrict__ hashes,
                                                   int* __restrict__ sidx,
                                                   unsigned short* __restrict__ hs_pack)
{
  __shared__ unsigned char bucket_s[S_LEN];
  __shared__ int counts[16][257];
  __shared__ int bbase[16];
  int t = threadIdx.x;
  size_t base = (size_t)blockIdx.x * S_LEN;
  for (int e=0;e<16;e++) bucket_s[t + e*256] = (unsigned char)hashes[base + t + e*256];
  #pragma unroll
  for (int u=0;u<16;u++) counts[u][t]=0;
  if (t<16) counts[t][256]=0;
  __syncthreads();
  int s0 = t*16;
  for (int e=0;e<16;e++){ int u = bucket_s[s0+e]; counts[u][t]++; }
  __syncthreads();
  if (t < 16){
    int run=0;
    for (int tt=0; tt<256; tt++){ int c = counts[t][tt]; counts[t][tt]=run; run+=c; }
    counts[t][256]=run;
  }
  __syncthreads();
  if (t==0){
    int run=0;
    for (int u=0;u<16;u++){ bbase[u]=run; run += counts[u][256]; }
  }
  __syncthreads();
  for (int e=0;e<16;e++){
    int s = s0+e; int u = bucket_s[s];
    int pos = bbase[u] + counts[u][t]; counts[u][t]++;
    sidx[base+pos] = s;
    hs_pack[base+pos] = (unsigned short)(s | (u<<12));
  }
}

// ---------- gather: sorted bf16 K-hat rows + transposed V ----------
// ksort[brh][pos][d]  = q[token][h,d] * invn[token]   (bf16)
// vsortT[brh][d][pos] = v[token][h,d]                 (bf16, transposed in LDS)
#define GST 136
__global__ __launch_bounds__(256) void gather_kernel(
    const float* __restrict__ qv, const float* __restrict__ invn,
    const int* __restrict__ sidx,
    unsigned short* __restrict__ ksort, unsigned short* __restrict__ vsortT)
{
  __shared__ int tok_s[256];
  __shared__ float sc_s[256];
  __shared__ unsigned short v_sub[64*GST];
  const int t = threadIdx.x;
  const int brh = blockIdx.x >> 4, pc = blockIdx.x & 15;
  const int b = brh >> 4;
  const int h = brh & 7;
  const size_t base_s = (size_t)brh * S_LEN;
  const int pos0 = pc * 256;
  {
    int tok = sidx[base_s + pos0 + t];
    tok_s[t] = tok;
    sc_s[t] = invn[tok*B_SZ + b];
  }
  __syncthreads();
  // ksort: coalesced row-major bf16
  #pragma unroll 4
  for (int i=0;i<16;i++){
    int slot = i*256 + t;
    int pos = slot >> 4, g = slot & 15;
    int tok = tok_s[pos]; float sc = sc_s[pos];
    const float* src = qv + ((size_t)tok*B_SZ + b)*QV_STRIDE + h*D_HEAD + g*8;
    float4 f0 = *(const float4*)src, f1 = *(const float4*)(src+4);
    uint4 u = { bpack2(f0.x*sc, f0.y*sc), bpack2(f0.z*sc, f0.w*sc),
                bpack2(f1.x*sc, f1.y*sc), bpack2(f1.z*sc, f1.w*sc) };
    *(uint4*)&ksort[(base_s + pos0 + pos)*128 + g*8] = u;
  }
  // vsortT: 4 sub-tiles of 64 pos, LDS transpose
  for (int sub=0; sub<4; sub++){
    __syncthreads();
    #pragma unroll
    for (int i=0;i<4;i++){
      int slot = i*256 + t;
      int pr = slot >> 4, g = slot & 15;
      int tok = tok_s[sub*64 + pr];
      const float* src = qv + ((size_t)tok*B_SZ + b)*QV_STRIDE + 1024 + h*D_HEAD + g*8;
      float4 f0 = *(const float4*)src, f1 = *(const float4*)(src+4);
      uint4 u = { bpack2(f0.x,f0.y), bpack2(f0.z,f0.w), bpack2(f1.x,f1.y), bpack2(f1.z,f1.w) };
      *(uint4*)&v_sub[pr*GST + g*8] = u;
    }
    __syncthreads();
    #pragma unroll
    for (int i=0;i<8;i++){
      int oslot = i*256 + t;             // 2048 = 128 d x 16 pos-groups
      int d = oslot >> 4, p4 = (oslot & 15)*4;
      unsigned a0 = v_sub[(p4+0)*GST + d];
      unsigned a1 = v_sub[(p4+1)*GST + d];
      unsigned a2 = v_sub[(p4+2)*GST + d];
      unsigned a3 = v_sub[(p4+3)*GST + d];
      uint2 o = { a0 | (a1<<16), a2 | (a3<<16) };
      *(uint2*)&vsortT[(size_t)brh*524288 + (size_t)d*4096 + pos0 + sub*64 + p4] = o;
    }
  }
}

// ---------- MFMA chunked LSH attention ----------
// Reference quirk (silent broadcast): for query at sorted position p=n*64+c,
// scores/values use win(n), but BOTH masks compare vs win(c).
// S rows post-scaled by SCALE*nrm[token] (Q = k-hat * SCALE*nrm exactly up to
// smooth fp noise). Full 192-wide softmax in registers; P via LDS (bf16).
#define KST 136
#define VST 72
#define PST 200
__device__ inline int swzg(int row, int g){ return (g ^ (row & 7)) << 3; }

__global__ __launch_bounds__(256) void attn_mfma_kernel(
    const unsigned short* __restrict__ ksort, const unsigned short* __restrict__ vsortT,
    const float* __restrict__ nrm, const unsigned short* __restrict__ hs_pack,
    unsigned short* __restrict__ o_r16, float* __restrict__ lse_g)
{
  __shared__ unsigned short kv_un[128*VST];          // 9216 u16: K chunk (64x136) or V^T chunk (128x72)
  __shared__ unsigned short p_sh[64*PST];
  __shared__ __align__(16) unsigned short pack_s[S_LEN];
  __shared__ float srow_s[64];

  const int t = threadIdx.x;
  const int bid = blockIdx.x;
  const int nc = bid & 63;
  const int brh = bid >> 6;
  const int b = brh >> 4;
  const size_t base_s = (size_t)brh * S_LEN;

  {
    const uint4* src = (const uint4*)(hs_pack + base_s);
    uint4* dst = (uint4*)pack_s;
    dst[t]       = src[t];
    dst[256 + t] = src[256 + t];
  }
  __syncthreads();
  if (t < 64){
    int tok = pack_s[nc*64 + t] & 0xfff;
    srow_s[t] = SCALE_F * nrm[tok*B_SZ + b];
  }

  const int lane = t & 63, wid = t >> 6;
  const int mw = wid * 16;                 // wave's 16 query rows
  const int lr = lane & 15, lg = lane >> 4;

  f32x4 acc[12];
  #pragma unroll
  for (int i=0;i<12;i++) acc[i] = (f32x4){0.f,0.f,0.f,0.f};
  short8 aq[4];

  // ---- QK^T: window chunks, w=1 first (supplies Q fragments) ----
  const int worder[3] = {1, 0, 2};
  #pragma unroll
  for (int wi=0; wi<3; wi++){
    int w = worder[wi];
    int cwch = (nc + w + 63) & 63;
    __syncthreads();                       // also covers srow_s on first iter
    #pragma unroll
    for (int i=0;i<4;i++){
      int slot = i*256 + t;
      int row = slot >> 4, g = slot & 15;
      uint4 u = *(const uint4*)&ksort[(base_s + cwch*64 + row)*128 + g*8];
      *(uint4*)&kv_un[row*KST + swzg(row, g)] = u;
    }
    __syncthreads();
    if (wi==0){
      #pragma unroll
      for (int ks=0; ks<4; ks++)
        aq[ks] = *(const short8*)&kv_un[(mw+lr)*KST + swzg(mw+lr, ks*4+lg)];
    }
    #pragma unroll
    for (int ks=0; ks<4; ks++){
      #pragma unroll
      for (int k4=0; k4<4; k4++){
        short8 bk = *(const short8*)&kv_un[(k4*16+lr)*KST + swzg(k4*16+lr, ks*4+lg)];
        acc[w*4+k4] = __builtin_amdgcn_mfma_f32_16x16x32_bf16(aq[ks], bk, acc[w*4+k4], 0,0,0);
      }
    }
  }

  // ---- scale + masks + softmax (C-layout: col=lr, rows mw+lg*4+r) ----
  unsigned pq[4]; float sr[4]; int c_[4]; float linv[4];
  #pragma unroll
  for (int r=0;r<4;r++){
    c_[r] = mw + lg*4 + r;
    pq[r] = pack_s[nc*64 + c_[r]];
    sr[r] = srow_s[c_[r]];
  }
  #pragma unroll
  for (int ti=0; ti<12; ti++){
    int w = ti >> 2, k4 = ti & 3;
    #pragma unroll
    for (int r=0;r<4;r++){
      int mc = (c_[r] + w + 63) & 63;
      unsigned e = pack_s[mc*64 + k4*16 + lr];
      float s = acc[ti][r] * sr[r];
      s = ((e>>12) == (pq[r]>>12)) ? s : NEG_F;
      if ((e & 0xfffu) == (pq[r] & 0xfffu)) s = NEG_SELF_F;
      acc[ti][r] = s;
    }
  }
  #pragma unroll
  for (int r=0;r<4;r++){
    float m = acc[0][r];
    #pragma unroll
    for (int ti=1; ti<12; ti++) m = fmaxf(m, acc[ti][r]);
    #pragma unroll
    for (int off=1; off<16; off<<=1) m = fmaxf(m, __shfl_xor(m, off));
    float l = 0.f;
    #pragma unroll
    for (int ti=0; ti<12; ti++){
      float p = __expf(acc[ti][r] - m);
      l += p;
      int wpos = (ti>>2)*64 + (ti&3)*16 + lr;
      p_sh[c_[r]*PST + (((wpos>>3) ^ (c_[r]&7))<<3) + (wpos&7)] = (unsigned short)bfr(p);
    }
    #pragma unroll
    for (int off=1; off<16; off<<=1) l += __shfl_xor(l, off);
    linv[r] = 1.0f / l;
    if (lr == 0) lse_g[base_s + (pq[r] & 0xfffu)] = m + logf(l);
  }

  // ---- PV ----
  f32x4 oacc[8];
  #pragma unroll
  for (int i=0;i<8;i++) oacc[i] = (f32x4){0.f,0.f,0.f,0.f};
  for (int w=0; w<3; w++){
    int cwch = (nc + w + 63) & 63;
    __syncthreads();                       // p_sh written; kv_un free
    #pragma unroll
    for (int i=0;i<4;i++){
      int slot = i*256 + t;                // 1024 = 128 d x 8 key-groups
      int d = slot >> 3, kg = slot & 7;
      uint4 u = *(const uint4*)&vsortT[(size_t)brh*524288 + (size_t)d*4096 + cwch*64 + kg*8];
      *(uint4*)&kv_un[d*VST + swzg(d, kg)] = u;
    }
    __syncthreads();
    short8 ap[2];
    #pragma unroll
    for (int ks=0; ks<2; ks++){
      int g = w*8 + ks*4 + lg;
      ap[ks] = *(const short8*)&p_sh[(mw+lr)*PST + ((g ^ ((mw+lr)&7))<<3)];
    }
    #pragma unroll
    for (int ks=0; ks<2; ks++)
      #pragma unroll
      for (int dt=0; dt<8; dt++){
        short8 bv = *(const short8*)&kv_un[(dt*16+lr)*VST + swzg(dt*16+lr, ks*4+lg)];
        oacc[dt] = __builtin_amdgcn_mfma_f32_16x16x32_bf16(ap[ks], bv, oacc[dt], 0,0,0);
      }
  }

  // ---- epilogue: bf16 scatter by token ----
  #pragma unroll
  for (int r=0;r<4;r++){
    int tok = pq[r] & 0xfff;
    size_t ob = (base_s + tok) * 128;
    #pragma unroll
    for (int dt=0; dt<8; dt++)
      o_r16[ob + dt*16 + lr] = (unsigned short)bfr(oacc[dt][r] * linv[r]);
  }
}

// ---------- launch ----------
extern "C" void kernel_launch(void* const* d_in, const int* in_sizes, int n_in,
                              void* d_out, int out_size, void* d_ws, size_t ws_size,
                              hipStream_t stream)
{
  (void)in_sizes; (void)n_in; (void)out_size; (void)ws_size;
  const float* x  = (const float*)d_in[0];
  const float* wq = (const float*)d_in[1];
  const float* bq = (const float*)d_in[2];
  const float* wv = (const float*)d_in[3];
  const float* bv = (const float*)d_in[4];
  const float* wo = (const float*)d_in[5];
  const float* bo = (const float*)d_in[6];
  const float* hw = (const float*)d_in[7];
  float* out = (float*)d_out;

  float* ws    = (float*)d_ws;
  float* qv    = ws;                          // [8192][2048] q|v fp32
  float* invn  = ws + 16777216;               // [8192]
  float* nrm   = ws + 16785408;               // [8192]
  int*   hashes= (int*)(ws + 16793600);       // [B,R,H,S]
  int*   sidx  = (int*)(ws + 16924672);       // [B,R,H,S]
  float* lse   = ws + 17055744;               // [B,R,H,S]
  unsigned short* o_r16   = (unsigned short*)(ws + 17186816);  // [32][4096][128] bf16 (written at attn)
  unsigned short* x16     = (unsigned short*)(ws + 17186816);  // overlays o_r16 front 16MB (dead before attn)
  unsigned short* wv16    = (unsigned short*)(ws + 21381120);  // overlays o_r16 tail (dead before attn)
  unsigned short* ksort   = (unsigned short*)(ws + 25575424);  // [32][4096][128] bf16
  unsigned short* vsortT  = (unsigned short*)(ws + 33964032);  // [32][128][4096] bf16
  unsigned short* hs_pack = (unsigned short*)(ws + 42352640);  // [B,R,H,S] packed

  cvt_bf16_kernel<<<dim3(4096), 256, 0, stream>>>(x,  x16,  1048576);   // 8192*1024/8
  cvt_bf16_kernel<<<dim3(512),  256, 0, stream>>>(wv, wv16, 131072);    // 1024*1024/8
  gemm_f32_kernel<<<dim3(8,64), 256, 0, stream>>>(x, wq, bq, qv, 1024, 1024, QV_STRIDE);
  gemm_bf16gl_kernel<<<dim3(8,64), 256, 0, stream>>>(x16, wv16, bv, qv + 1024, 1024, QV_STRIDE);
  invnorm_kernel<<<dim3(8192), 256, 0, stream>>>(qv, invn, nrm);
  hash32_kernel<<<dim3(512), 256, 0, stream>>>(qv, nrm, hw, hashes);
  sort_kernel<<<dim3(32), 256, 0, stream>>>(hashes, sidx, hs_pack);
  gather_kernel<<<dim3(512), 256, 0, stream>>>(qv, invn, sidx, ksort, vsortT);
  attn_mfma_kernel<<<dim3(2048), 256, 0, stream>>>(ksort, vsortT, nrm, hs_pack, o_r16, lse);
  gemm_out_kernel<<<dim3(8,64), 256, 0, stream>>>(o_r16, lse, wo, bo, out);
}